// Round 6
// baseline (252.773 us; speedup 1.0000x reference)
//
#include <hip/hip_runtime.h>
#include <hip/hip_bf16.h>
#include <math.h>

// ---- problem constants ----
// bs=32, S=512, D=256, HS=4 heads (head dim = D = 256!), NT = 16384 tokens
// patch: NP=16 patches x P=16, CC=128, HP=4 heads x CE=32

typedef __attribute__((ext_vector_type(8))) short bf16x8;
typedef __attribute__((ext_vector_type(4))) float f32x4;

__device__ __forceinline__ float bf_lo(unsigned u){ return __uint_as_float(u << 16); }
__device__ __forceinline__ float bf_hi(unsigned u){ return __uint_as_float(u & 0xFFFF0000u); }
__device__ __forceinline__ unsigned short f2bf(float f){
  unsigned u = __float_as_uint(f);
  return (unsigned short)((u + 0x7FFFu + ((u >> 16) & 1u)) >> 16);   // RNE
}
__device__ __forceinline__ unsigned pack2bf(float a, float b){
  return (unsigned)f2bf(a) | ((unsigned)f2bf(b) << 16);
}
__device__ __forceinline__ bf16x8 pack8(float a0,float a1,float a2,float a3,
                                        float a4,float a5,float a6,float a7){
  union { bf16x8 v; unsigned u[4]; } t;
  t.u[0]=pack2bf(a0,a1); t.u[1]=pack2bf(a2,a3);
  t.u[2]=pack2bf(a4,a5); t.u[3]=pack2bf(a6,a7);
  return t.v;
}
// async 16B global->LDS (dest = wave-uniform base + lane*16)
__device__ __forceinline__ void gld16(const void* g, void* l){
  __builtin_amdgcn_global_load_lds((const __attribute__((address_space(1))) void*)g,
                                   (__attribute__((address_space(3))) void*)l, 16, 0, 0);
}

// ---------------------------------------------------------------------------
// cvt: f32 -> bf16, vectorized x4
// ---------------------------------------------------------------------------
__global__ __launch_bounds__(256) void k_cvt(const float* __restrict__ src,
                                             unsigned short* __restrict__ dst, int n4)
{
  int i = blockIdx.x * 256 + threadIdx.x;
  if (i < n4){
    float4 v = ((const float4*)src)[i];
    ushort4 o;
    o.x = f2bf(v.x); o.y = f2bf(v.y); o.z = f2bf(v.z); o.w = f2bf(v.w);
    ((ushort4*)dst)[i] = o;
  }
}

// ---------------------------------------------------------------------------
// k_packw: pre-pack patch weights into per-lane MFMA B-fragment layout.
// ---------------------------------------------------------------------------
__global__ __launch_bounds__(256) void k_packw(
    const float* __restrict__ Wqc, const float* __restrict__ Wkc,
    const float* __restrict__ Wvl, const float* __restrict__ Wlo,
    unsigned short* __restrict__ Wp)
{
  int it = blockIdx.x * 256 + threadIdx.x;     // 28*64 = 1792 items
  if (it >= 1792) return;
  int ch = it >> 6, lane = it & 63;
  int g = lane >> 4, li = lane & 15;
  unsigned short o[8];
  if (ch < 24){
    int m = ch >> 3, nc = ch & 7;
    const float* W = (m == 0) ? Wqc : (m == 1 ? Wkc : Wvl);
    int c = nc * 16 + li;
    #pragma unroll
    for (int j = 0; j < 8; ++j){
      int k = g * 8 + j;
      o[j] = (k < 16) ? f2bf(W[c * 16 + k]) : (unsigned short)0;
    }
  } else {
    int kc = ch - 24;
    #pragma unroll
    for (int j = 0; j < 8; ++j){
      int k = kc * 32 + g * 8 + j;
      o[j] = f2bf(Wlo[li * 128 + k]);
    }
  }
  #pragma unroll
  for (int j = 0; j < 8; ++j) Wp[it * 8 + j] = o[j];
}

// ---------------------------------------------------------------------------
// k_gemm: C[M,128-tile] = A[M,K](bf16) . W[N,K](bf16)^T, 128x128 block tile,
// 4 waves (64x64/wave), BK=64, dbuf global_load_lds w/ pre-swizzled source.
// EPI 0: bias + scatter to QKV bf16 [bh][s][d].  EPI 1: bias + resid -> f32.
// ---------------------------------------------------------------------------
template<int EPI>
__global__ __launch_bounds__(256) void k_gemm(
    const unsigned short* __restrict__ A,   // [M,K] bf16
    const unsigned short* __restrict__ W,   // [N,K] bf16
    const float* __restrict__ b0,
    const float* __restrict__ b1,
    const float* __restrict__ b2,
    const float* __restrict__ resid,        // EPI==1: f32 [M,256]
    void* __restrict__ outp,                // EPI==0: Qw base; EPI==1: f32 out
    unsigned short* __restrict__ Kw_,
    unsigned short* __restrict__ Vw_,
    int K)
{
  extern __shared__ char sm[];
  const int tid = threadIdx.x;
  const int wid = tid >> 6, lane = tid & 63;
  const int g = lane >> 4, li = lane & 15;
  const int wm = wid >> 1, wn = wid & 1;
  const int m0 = blockIdx.x << 7, n0 = blockIdx.y << 7;

  const unsigned short* Ab = A + (size_t)m0 * K;
  const unsigned short* Wb = W + (size_t)n0 * K;

  auto stage = [&](char* dst, const unsigned short* src, int k0){
    #pragma unroll
    for (int r = 0; r < 4; ++r){
      int row = (r << 5) + (tid >> 3);
      int cb  = (tid & 7) << 4;
      int cbs = cb ^ ((row & 7) << 4);
      gld16(src + row * K + k0 + (cbs >> 1), dst + (r << 12) + (wid << 10));
    }
  };

  f32x4 acc[4][4];
  #pragma unroll
  for (int mf = 0; mf < 4; ++mf)
    #pragma unroll
    for (int nf = 0; nf < 4; ++nf) acc[mf][nf] = (f32x4){0.f,0.f,0.f,0.f};

  const int nk = K >> 6;
  stage(sm, Ab, 0); stage(sm + 32768, Wb, 0);
  for (int kt = 0; kt < nk; ++kt){
    char* Acur = (kt & 1) ? (sm + 16384) : sm;
    char* Wcur = (kt & 1) ? (sm + 49152) : (sm + 32768);
    if (kt + 1 < nk){
      char* Anxt = (kt & 1) ? sm : (sm + 16384);
      char* Wnxt = (kt & 1) ? (sm + 32768) : (sm + 49152);
      stage(Anxt, Ab, (kt + 1) << 6);
      stage(Wnxt, Wb, (kt + 1) << 6);
    }
    __syncthreads();
    bf16x8 af[2][4], wf[2][4];
    #pragma unroll
    for (int kk = 0; kk < 2; ++kk){
      #pragma unroll
      for (int mf = 0; mf < 4; ++mf){
        int row  = (wm << 6) + (mf << 4) + li;
        int colb = ((kk << 6) + (g << 4)) ^ ((row & 7) << 4);
        af[kk][mf] = *(const bf16x8*)(Acur + (row << 7) + colb);
      }
      #pragma unroll
      for (int nf = 0; nf < 4; ++nf){
        int row  = (wn << 6) + (nf << 4) + li;
        int colb = ((kk << 6) + (g << 4)) ^ ((row & 7) << 4);
        wf[kk][nf] = *(const bf16x8*)(Wcur + (row << 7) + colb);
      }
    }
    #pragma unroll
    for (int kk = 0; kk < 2; ++kk)
      #pragma unroll
      for (int mf = 0; mf < 4; ++mf)
        #pragma unroll
        for (int nf = 0; nf < 4; ++nf)
          acc[mf][nf] = __builtin_amdgcn_mfma_f32_16x16x32_bf16(af[kk][mf], wf[kk][nf], acc[mf][nf], 0, 0, 0);
    __syncthreads();
  }

  // lane holds C[m0 + wm*64 + mf*16 + g*4 + r][n0 + wn*64 + nf*16 + li]
  if (EPI == 0){
    const int chunk = n0 >> 10;
    const float* bias = (chunk == 0) ? b0 : (chunk == 1 ? b1 : b2);
    unsigned short* dst = (chunk == 0) ? (unsigned short*)outp : (chunk == 1 ? Kw_ : Vw_);
    const int nq0 = n0 & 1023;
    const int h = nq0 >> 8;                 // uniform per block
    #pragma unroll
    for (int nf = 0; nf < 4; ++nf){
      const int nq = nq0 + (wn << 6) + (nf << 4) + li;
      const int d = nq & 255;
      const float bv = bias[nq];
      #pragma unroll
      for (int mf = 0; mf < 4; ++mf){
        const int mbase = m0 + (wm << 6) + (mf << 4) + (g << 2);
        #pragma unroll
        for (int r = 0; r < 4; ++r){
          const int m = mbase + r;
          const int b = m >> 9, s = m & 511;
          dst[(size_t)((((b << 2) + h) << 9) + s) * 256 + d] = f2bf(acc[mf][nf][r] + bv);
        }
      }
    }
  } else {
    float* op = (float*)outp;
    #pragma unroll
    for (int nf = 0; nf < 4; ++nf){
      const int n = n0 + (wn << 6) + (nf << 4) + li;
      const float bv = b0[n];
      #pragma unroll
      for (int mf = 0; mf < 4; ++mf){
        const int mbase = m0 + (wm << 6) + (mf << 4) + (g << 2);
        #pragma unroll
        for (int r = 0; r < 4; ++r){
          const int m = mbase + r;
          op[(size_t)m * 256 + n] = acc[mf][nf][r] + bv + resid[(size_t)m * 256 + n];
        }
      }
    }
  }
}

// ---------------------------------------------------------------------------
// k_ln: LN (mean/std, ddof=1, no eps) over rows of 256. wave per token.
// ---------------------------------------------------------------------------
__global__ __launch_bounds__(512) void k_ln(const float* __restrict__ src,
                                            float* __restrict__ dst)
{
  const int lane = threadIdx.x & 63;
  const int n    = blockIdx.x * 8 + (threadIdx.x >> 6);
  float4 v = *(const float4*)(src + (size_t)n * 256 + lane * 4);
  float sum = v.x + v.y + v.z + v.w;
  #pragma unroll
  for (int mk = 32; mk >= 1; mk >>= 1) sum += __shfl_xor(sum, mk);
  float mean = sum * (1.0f / 256.0f);
  float4 e; e.x = v.x - mean; e.y = v.y - mean; e.z = v.z - mean; e.w = v.w - mean;
  float sq = e.x*e.x + e.y*e.y + e.z*e.z + e.w*e.w;
  #pragma unroll
  for (int mk = 32; mk >= 1; mk >>= 1) sq += __shfl_xor(sq, mk);
  float inv = rsqrtf(sq * (1.0f / 255.0f));
  e.x *= inv; e.y *= inv; e.z *= inv; e.w *= inv;
  *(float4*)(dst + (size_t)n * 256 + lane * 4) = e;
}

// ---------------------------------------------------------------------------
// K1b: V transpose per bh: Vt[bh][d][s] from Vw[bh][s][d], 64x64 tiles.
// ---------------------------------------------------------------------------
__global__ __launch_bounds__(256) void k_vt(const unsigned short* __restrict__ Vw,
                                            unsigned short* __restrict__ Vt)
{
  __shared__ unsigned short tile[64][72];
  const int tid = threadIdx.x;
  const int s0 = blockIdx.x << 6, d0 = blockIdx.y << 6, bh = blockIdx.z;
  const unsigned short* src = Vw + (bh * 512 + s0) * 256 + d0;
  #pragma unroll
  for (int p = 0; p < 2; ++p){
    int idx = p * 256 + tid;
    int sl = idx >> 3, db = (idx & 7) * 8;
    *(uint4*)&tile[sl][db] = *(const uint4*)(src + sl * 256 + db);
  }
  __syncthreads();
  #pragma unroll
  for (int p = 0; p < 2; ++p){
    int idx = p * 256 + tid;
    int dl = idx >> 3, sb = (idx & 7) * 8, m = idx & 7;
    unsigned short r[8] __attribute__((aligned(16)));
    #pragma unroll
    for (int k = 0; k < 8; ++k){
      int kk = (k + m) & 7;
      r[kk] = tile[sb + kk][dl];
    }
    *(uint4*)(Vt + (bh * 256 + d0 + dl) * 512 + s0 + sb) = *(uint4*)r;
  }
}

// ---------------------------------------------------------------------------
// K2: MFMA flash attention. KVBLK=32, 16 iters, 76KB LDS -> 2 blocks/CU.
// 8 waves x 16 q-rows = 128 q/block. XCD-swizzled block ids. Defer-max.
// LDS: K dbuf 2x16K @0/16384, V dbuf 2x16K @32768/49152, P 8x1.5K @65536.
// ---------------------------------------------------------------------------
__global__ __launch_bounds__(512) void k_attn(const unsigned short* __restrict__ Qw,
                                              const unsigned short* __restrict__ Kw,
                                              const unsigned short* __restrict__ Vt,
                                              unsigned short* __restrict__ Ow)
{
  extern __shared__ char smem[];
  const int tid  = threadIdx.x;
  const int wid  = tid >> 6, lane = tid & 63;
  const int g    = lane >> 4, li = lane & 15, l7 = lane & 7;
  // XCD swizzle: 4 q-blocks of one bh land on one XCD (512 = 8 XCD x 64)
  const int dd   = blockIdx.x + (blockIdx.y << 2);
  const int nl   = ((dd & 7) << 6) + (dd >> 3);
  const int bh   = nl >> 2;
  const int sblk = (nl & 3) << 7;
  const int q0   = sblk + (wid << 4);

  char* const PB = smem + 65536 + wid * 1536;

  auto stageK = [&](char* kbuf, int t0){
    const unsigned short* base = Kw + ((bh << 9) + t0 + (wid << 2)) * 256;
    char* dst = kbuf + (wid << 11);
    #pragma unroll
    for (int c = 0; c < 2; ++c){
      int r  = (c << 1) + (lane >> 5);                 // 0..3 (row in wave)
      int s7 = ((wid & 1) << 2) | r;                   // (tile row)&7
      int cs = ((((lane & 31) << 4) ^ (s7 << 4)) >> 1);
      gld16(base + (r << 8) + cs, dst + (c << 10));
    }
  };
  auto stageV = [&](char* vbuf, int t0){
    const unsigned short* base = Vt + (bh * 256 + (wid << 5)) * 512 + t0;
    char* dst = vbuf + (wid << 11);
    #pragma unroll
    for (int c = 0; c < 2; ++c){
      int r  = (c << 4) + (lane >> 2);                 // 0..31 (row in wave)
      int cs = (((lane & 3) ^ (r & 3)) << 3);          // 16B-chunk XOR row&3
      gld16(base + (r << 9) + cs, dst + (c << 10));
    }
  };

  stageK(smem, 0);
  stageV(smem + 32768, 0);

  // ---- Q B-frags: lane holds Q[q0+li][kk*32 + g*8 .. +7] ----
  bf16x8 qf[8];
  {
    const unsigned short* qp = Qw + ((bh << 9) + q0 + li) * 256 + (g << 3);
    #pragma unroll
    for (int kk = 0; kk < 8; ++kk)
      qf[kk] = *(const bf16x8*)(qp + (kk << 5));
  }

  f32x4 o[16];
  #pragma unroll
  for (int df = 0; df < 16; ++df) o[df] = (f32x4){0.f,0.f,0.f,0.f};
  float mrun = -3.0e38f, lrun = 0.f;

  __syncthreads();
  const float inv256 = 1.0f / 256.0f;

  for (int t = 0; t < 16; ++t){
    char* kb = (t & 1) ? (smem + 16384) : smem;
    char* vb = (t & 1) ? (smem + 49152) : (smem + 32768);
    if (t < 15){
      char* kn = (t & 1) ? smem : (smem + 16384);
      char* vn = (t & 1) ? (smem + 32768) : (smem + 49152);
      stageK(kn, (t + 1) << 5);
      stageV(vn, (t + 1) << 5);
    }

    // ---- S^T(32t x 16si) = K . Q^T ----
    f32x4 st[2];
    #pragma unroll
    for (int tf = 0; tf < 2; ++tf){
      st[tf] = (f32x4){0.f,0.f,0.f,0.f};
      const int rowb = ((tf << 4) + li) << 9;
      #pragma unroll
      for (int kk = 0; kk < 8; ++kk){
        const int colb = ((kk << 6) + (g << 4)) ^ (l7 << 4);
        bf16x8 kf = *(const bf16x8*)(kb + rowb + colb);
        st[tf] = __builtin_amdgcn_mfma_f32_16x16x32_bf16(kf, qf[kk], st[tf], 0, 0, 0);
      }
    }

    // ---- online softmax with defer-max (THR=8) ----
    float s[8];
    #pragma unroll
    for (int tf = 0; tf < 2; ++tf){
      s[tf*4+0] = st[tf].x * inv256; s[tf*4+1] = st[tf].y * inv256;
      s[tf*4+2] = st[tf].z * inv256; s[tf*4+3] = st[tf].w * inv256;
    }
    float pmax = s[0];
    #pragma unroll
    for (int i = 1; i < 8; ++i) pmax = fmaxf(pmax, s[i]);
    pmax = fmaxf(pmax, __shfl_xor(pmax, 16));
    pmax = fmaxf(pmax, __shfl_xor(pmax, 32));
    if (!__all(pmax - mrun <= 8.0f)){
      float mnew = fmaxf(mrun, pmax);
      float corr = __expf(mrun - mnew);
      lrun *= corr;
      #pragma unroll
      for (int df = 0; df < 16; ++df) o[df] *= corr;
      mrun = mnew;
    }
    float psum = 0.f;
    #pragma unroll
    for (int i = 0; i < 8; ++i){ s[i] = __expf(s[i] - mrun); psum += s[i]; }
    psum += __shfl_xor(psum, 16);
    psum += __shfl_xor(psum, 32);
    lrun += psum;

    // ---- P -> P_lds[si][t] bf16 (80B rows), per-wave private ----
    #pragma unroll
    for (int tf = 0; tf < 2; ++tf){
      uint2 pk; pk.x = pack2bf(s[tf*4+0], s[tf*4+1]); pk.y = pack2bf(s[tf*4+2], s[tf*4+3]);
      *(uint2*)(PB + li * 80 + (tf << 5) + (g << 3)) = pk;
    }
    __asm__ volatile("s_waitcnt lgkmcnt(0)" ::: "memory");
    __builtin_amdgcn_sched_barrier(0);

    // ---- O^T(256d x 16si) += Vt_tile . P^T (K=32, one shot) ----
    bf16x8 pb = *(const bf16x8*)(PB + li * 80 + (g << 4));
    #pragma unroll
    for (int df = 0; df < 16; ++df){
      bf16x8 va = *(const bf16x8*)(vb + (((df << 4) + li) << 6) + ((g ^ (li & 3)) << 4));
      o[df] = __builtin_amdgcn_mfma_f32_16x16x32_bf16(va, pb, o[df], 0, 0, 0);
    }
    __syncthreads();
  }

  // ---- epilogue: O /= l, transpose via LDS (8KB/wave), coalesced store ----
  float inv = 1.0f / lrun;
  #pragma unroll
  for (int df = 0; df < 16; ++df) o[df] *= inv;

  char* const OT = smem + (wid << 13);
  #pragma unroll
  for (int df = 0; df < 16; ++df){
    uint2 pk; pk.x = pack2bf(o[df].x, o[df].y); pk.y = pack2bf(o[df].z, o[df].w);
    const int addr = (li << 9) + (((df << 5) + (g << 3)) ^ (l7 << 4));
    *(uint2*)(OT + addr) = pk;
  }
  __asm__ volatile("s_waitcnt lgkmcnt(0)" ::: "memory");
  __builtin_amdgcn_sched_barrier(0);
  const int b = bh >> 2, h = bh & 3;
  #pragma unroll
  for (int p = 0; p < 8; ++p){
    const int row  = (p << 1) + (lane >> 5);
    const int colb = ((lane & 31) << 4) ^ ((row & 7) << 4);
    uint4 vv = *(const uint4*)(OT + (row << 9) + colb);
    const int d0 = (lane & 31) << 3;
    *(uint4*)(Ow + ((b << 9) + sblk + (wid << 4) + row) * 1024 + (h << 8) + d0) = vv;
  }
}

// ---------------------------------------------------------------------------
// K4: patch attention, wave-per-token MFMA, no __syncthreads.
// ---------------------------------------------------------------------------
__global__ __launch_bounds__(256) void k_patch2(
    const float* __restrict__ x1,
    const unsigned short* __restrict__ Wp,
    const float* __restrict__ bqc, const float* __restrict__ bkc,
    const float* __restrict__ bvl, const float* __restrict__ blo,
    unsigned short* __restrict__ yb)
{
  extern __shared__ char lds[];
  const int tid = threadIdx.x;
  const int wid = tid >> 6, lane = tid & 63;
  const int g = lane >> 4, li = lane & 15;
  const int n = (blockIdx.x << 2) + wid;

  char* const QB = lds + (wid << 14);
  char* const KB = QB + 4096;
  char* const VB = QB + 8192;
  char* const PB = QB + 14336;
  const int swz = (li & 7) << 4;
  const bf16x8 zf = (bf16x8){0,0,0,0,0,0,0,0};

  bf16x8 xf = zf;
  if (g < 2){
    const float* xr = x1 + (size_t)n * 256 + li * 16 + g * 8;
    float4 a = *(const float4*)xr;
    float4 b = *(const float4*)(xr + 4);
    xf = pack8(a.x,a.y,a.z,a.w, b.x,b.y,b.z,b.w);
  }

  #pragma unroll
  for (int m = 0; m < 3; ++m){
    const float* bias = (m == 0) ? bqc : ((m == 1) ? bkc : bvl);
    #pragma unroll
    for (int nc = 0; nc < 8; ++nc){
      bf16x8 wf = *(const bf16x8*)(Wp + ((((m << 3) + nc) << 6) + lane) * 8);
      f32x4 c = __builtin_amdgcn_mfma_f32_16x16x32_bf16(xf, wf, (f32x4){0,0,0,0}, 0, 0, 0);
      float bv = bias[(nc << 4) + li];
      if (m < 2){
        char* B = (m == 0) ? QB : KB;
        #pragma unroll
        for (int r = 0; r < 4; ++r){
          int p = (g << 2) + r;
          *(unsigned short*)(B + (p << 8) + (((((nc << 4) + li) << 1)) ^ ((p & 7) << 4))) = f2bf(c[r] + bv);
        }
      } else {
        int cc = (nc << 4) + li;
        *(unsigned*)(VB + cc * 48 + (g << 3))     = pack2bf(c[0] + bv, c[1] + bv);
        *(unsigned*)(VB + cc * 48 + (g << 3) + 4) = pack2bf(c[2] + bv, c[3] + bv);
      }
    }
  }
  __asm__ volatile("s_waitcnt lgkmcnt(0)" ::: "memory");
  __builtin_amdgcn_sched_barrier(0);

  f32x4 of[8];
  #pragma unroll
  for (int i = 0; i < 8; ++i) of[i] = (f32x4){0,0,0,0};

  #pragma unroll
  for (int h = 0; h < 4; ++h){
    const int cb = (h << 6) + (g << 4);
    bf16x8 kf = *(const bf16x8*)(KB + (li << 8) + (cb ^ swz));
    bf16x8 qf = *(const bf16x8*)(QB + (li << 8) + (cb ^ swz));
    f32x4 st = __builtin_amdgcn_mfma_f32_16x16x32_bf16(kf, qf, (f32x4){0,0,0,0}, 0, 0, 0);
    float s0 = st[0]*0.0625f, s1 = st[1]*0.0625f, s2 = st[2]*0.0625f, s3 = st[3]*0.0625f;
    float mx = fmaxf(fmaxf(s0, s1), fmaxf(s2, s3));
    mx = fmaxf(mx, __shfl_xor(mx, 16));
    mx = fmaxf(mx, __shfl_xor(mx, 32));
    float e0 = __expf(s0-mx), e1 = __expf(s1-mx), e2 = __expf(s2-mx), e3 = __expf(s3-mx);
    float ss = e0 + e1 + e2 + e3;
    ss += __shfl_xor(ss, 16);
    ss += __shfl_xor(ss, 32);
    float inv = 1.0f / ss;
    e0 *= inv; e1 *= inv; e2 *= inv; e3 *= inv;
    *(unsigned*)(PB + li * 80 + (g << 3))     = pack2bf(e0, e1);
    *(unsigned*)(PB + li * 80 + (g << 3) + 4) = pack2bf(e2, e3);
    __asm__ volatile("s_waitcnt lgkmcnt(0)" ::: "memory");
    __builtin_amdgcn_sched_barrier(0);
    bf16x8 pf = zf;
    if (g < 2) pf = *(const bf16x8*)(PB + li * 80 + (g << 4));
    #pragma unroll
    for (int t = 0; t < 2; ++t){
      bf16x8 vf = zf;
      if (g < 2) vf = *(const bf16x8*)(VB + ((h << 5) + (t << 4) + li) * 48 + (g << 4));
      of[(h << 1) + t] = __builtin_amdgcn_mfma_f32_16x16x32_bf16(pf, vf, of[(h << 1) + t], 0, 0, 0);
    }
  }

  #pragma unroll
  for (int h = 0; h < 4; ++h)
    #pragma unroll
    for (int t = 0; t < 2; ++t){
      f32x4 c = of[(h << 1) + t];
      int cc = (h << 5) + (t << 4) + li;
      #pragma unroll
      for (int r = 0; r < 4; ++r){
        int p = (g << 2) + r;
        *(unsigned short*)(QB + (p << 8) + ((cc << 1) ^ ((p & 7) << 4))) = f2bf(c[r]);
      }
    }
  __asm__ volatile("s_waitcnt lgkmcnt(0)" ::: "memory");
  __builtin_amdgcn_sched_barrier(0);

  f32x4 y = (f32x4){0,0,0,0};
  #pragma unroll
  for (int kc = 0; kc < 4; ++kc){
    bf16x8 af = *(const bf16x8*)(QB + (li << 8) + ((((kc << 6) + (g << 4))) ^ swz));
    bf16x8 wf = *(const bf16x8*)(Wp + (((24 + kc) << 6) + lane) * 8);
    y = __builtin_amdgcn_mfma_f32_16x16x32_bf16(af, wf, y, 0, 0, 0);
  }
  float bv = blo[li];
  unsigned short* yr = yb + (size_t)n * 256 + li;
  #pragma unroll
  for (int r = 0; r < 4; ++r)
    yr[((g << 2) + r) << 4] = f2bf(y[r] + bv);
}

// ---------------------------------------------------------------------------
extern "C" void kernel_launch(void* const* d_in, const int* in_sizes, int n_in,
                              void* d_out, int out_size, void* d_ws, size_t ws_size,
                              hipStream_t stream)
{
  const float* x     = (const float*)d_in[0];
  const float* Wq    = (const float*)d_in[1];
  const float* bq    = (const float*)d_in[2];
  const float* Wk    = (const float*)d_in[3];
  const float* bk    = (const float*)d_in[4];
  const float* Wv    = (const float*)d_in[5];
  const float* bv    = (const float*)d_in[6];
  const float* Wlin1 = (const float*)d_in[7];
  const float* blin1 = (const float*)d_in[8];
  const float* Wqc   = (const float*)d_in[9];
  const float* bqc   = (const float*)d_in[10];
  const float* Wkc   = (const float*)d_in[11];
  const float* bkc   = (const float*)d_in[12];
  const float* Wvl   = (const float*)d_in[13];
  const float* bvl   = (const float*)d_in[14];
  const float* Wlo   = (const float*)d_in[15];
  const float* blo   = (const float*)d_in[16];
  const float* Wlout = (const float*)d_in[17];
  const float* blout = (const float*)d_in[18];
  float* out = (float*)d_out;

  char* w = (char*)d_ws;
  unsigned short* Qw  = (unsigned short*)w;
  unsigned short* yb  = (unsigned short*)w;
  unsigned short* Kw  = (unsigned short*)(w + 33554432);
  unsigned short* Vw  = (unsigned short*)(w + 67108864);
  unsigned short* xb  = (unsigned short*)(w + 100663296);
  unsigned short* Ow  = (unsigned short*)(w + 100663296);
  unsigned short* Vtw = (unsigned short*)(w + 134217728);
  float* x1raw  = (float*)(w + 134217728);
  float* outraw = (float*)(w + 134217728);
  float* x1     = (float*)(w + 150994944);
  unsigned short* Wqkvb  = (unsigned short*)(w + 167772160);
  unsigned short* Wlin1b = (unsigned short*)(w + 169345024);
  unsigned short* Wloutb = (unsigned short*)(w + 169869312);
  unsigned short* Wp     = (unsigned short*)(w + 170000384);

  hipFuncSetAttribute((const void*)k_attn, hipFuncAttributeMaxDynamicSharedMemorySize, 77824);
  hipFuncSetAttribute((const void*)k_gemm<0>, hipFuncAttributeMaxDynamicSharedMemorySize, 65536);
  hipFuncSetAttribute((const void*)k_gemm<1>, hipFuncAttributeMaxDynamicSharedMemorySize, 65536);
  hipFuncSetAttribute((const void*)k_patch2, hipFuncAttributeMaxDynamicSharedMemorySize, 65536);

  // ---- prep: dtype conversions + patch weight fragment packing ----
  k_cvt<<<4096, 256, 0, stream>>>(x, xb, 1048576);
  k_cvt<<<256, 256, 0, stream>>>(Wq, Wqkvb, 65536);
  k_cvt<<<256, 256, 0, stream>>>(Wk, Wqkvb + 262144, 65536);
  k_cvt<<<256, 256, 0, stream>>>(Wv, Wqkvb + 524288, 65536);
  k_cvt<<<256, 256, 0, stream>>>(Wlin1, Wlin1b, 65536);
  k_cvt<<<64, 256, 0, stream>>>(Wlout, Wloutb, 16384);
  k_packw<<<7, 256, 0, stream>>>(Wqc, Wkc, Wvl, Wlo, Wp);

  // ---- QKV projection (MFMA GEMM, scatter epilogue) ----
  k_gemm<0><<<dim3(128, 24), 256, 65536, stream>>>(xb, Wqkvb, bq, bk, bv,
                                                   nullptr, Qw, Kw, Vw, 256);
  k_vt  <<<dim3(8, 4, 128), 256, 0, stream>>>(Vw, Vtw);
  k_attn<<<dim3(4, 128), 512, 77824, stream>>>(Qw, Kw, Vtw, Ow);

  // ---- lin1 + LN ----
  k_gemm<1><<<dim3(128, 2), 256, 65536, stream>>>(Ow, Wlin1b, blin1, nullptr, nullptr,
                                                  x, x1raw, nullptr, nullptr, 1024);
  k_ln<<<2048, 512, 0, stream>>>(x1raw, x1);

  // ---- patch attention (wave-per-token MFMA) ----
  k_patch2<<<4096, 256, 65536, stream>>>(x1, Wp, bqc, bkc, bvl, blo, yb);

  // ---- Wlout + LN ----
  k_gemm<1><<<dim3(128, 2), 256, 65536, stream>>>(yb, Wloutb, blout, nullptr, nullptr,
                                                  x1, outraw, nullptr, nullptr, 256);
  k_ln<<<2048, 512, 0, stream>>>(outraw, out);
}